// Round 8
// baseline (326.140 us; speedup 1.0000x reference)
//
#include <hip/hip_runtime.h>

// GraphSAGE 2-layer inference.
// detect -> prep (x->fp8, W1/W2 -> MFMA-frag bf16) -> bucketed CSR build
//  -> agg1 = A_mean * x_fp8  (8-lane groups x 16B, shfl-distributed csr idx, fp32 acc, bf16 out)
//  -> fused MLP (bf16 MFMA): g = relu(agg1 @ W1T + b1) @ W2T -> fp8 (64B rows = 1 line/edge)
//  -> agg2 = A_mean * g_fp8 + b2 -> log_softmax (4-lane groups x 16B, fp32 out)
// Linear-commutes-with-mean: layer2 projects 256->64 BEFORE aggregation.
// fp8 halves gather bytes: agg1 compulsory L2-miss ~179->~92MB, agg2 1 line/edge.

typedef __attribute__((ext_vector_type(8))) short bf16x8;
typedef __attribute__((ext_vector_type(4))) float f32x4;
typedef __attribute__((ext_vector_type(2))) float f32x2;

#define BSHIFT 10
#define BMASK  1023
#define SRCMASK 0x1FFFF
#define TBIN   4096

#if __has_builtin(__builtin_amdgcn_cvt_pk_f32_fp8) && __has_builtin(__builtin_amdgcn_cvt_pk_fp8_f32)
#define HAVE_FP8_CVT 1
#else
#define HAVE_FP8_CVT 0
#endif

__device__ inline ushort f2bf(float f) {
  union { float f; unsigned u; } c; c.f = f;
  unsigned r = (c.u + 0x7fffu + ((c.u >> 16) & 1u)) >> 16;
  return (ushort)r;
}
__device__ inline float bf2f(ushort u) {
  union { unsigned u; float f; } c; c.u = ((unsigned)u) << 16;
  return c.f;
}

#if HAVE_FP8_CVT
// hi-select must be a compile-time constant -> template parameter.
template <bool HI>
__device__ inline f32x2 fp8x2f(unsigned w) {
  return __builtin_amdgcn_cvt_pk_f32_fp8((int)w, HI);
}
template <bool HI>
__device__ inline unsigned fp8pack2(unsigned old, float a, float b) {
  return (unsigned)__builtin_amdgcn_cvt_pk_fp8_f32(a, b, (int)old, HI);
}
#else
__device__ inline float fp8tof_1(unsigned b) {
  unsigned e = (b >> 3) & 15u, m = b & 7u;
  float v;
  if (e == 0) v = (float)m * 0x1p-9f;
  else { union { unsigned u; float f; } c; c.u = ((e + 120u) << 23) | (m << 20); v = c.f; }
  return (b & 0x80u) ? -v : v;
}
template <bool HI>
__device__ inline f32x2 fp8x2f(unsigned w) {
  unsigned sh = HI ? 16 : 0;
  f32x2 r;
  r.x = fp8tof_1((w >> sh) & 0xFFu);
  r.y = fp8tof_1((w >> (sh + 8)) & 0xFFu);
  return r;
}
__device__ inline unsigned f2fp8_1(float f) {
  float af = fabsf(f);
  unsigned s = (f < 0.f) ? 0x80u : 0u;
  if (!(af < 448.f)) return s | 0x7Eu;
  if (af < 0x1p-6f) {
    int m = (int)rintf(af * 512.0f);
    if (m >= 8) return s | 0x08u;
    return s | (unsigned)m;
  }
  int e;
  frexpf(af, &e);
  int E = e - 1;
  int q = (int)rintf(ldexpf(af, 3 - E));
  if (q >= 16) { q = 8; E += 1; if (E > 8) return s | 0x7Eu; }
  return s | ((unsigned)(E + 7) << 3) | ((unsigned)q & 7u);
}
template <bool HI>
__device__ inline unsigned fp8pack2(unsigned old, float a, float b) {
  unsigned pair = f2fp8_1(a) | (f2fp8_1(b) << 8);
  return HI ? ((old & 0x0000FFFFu) | (pair << 16)) : ((old & 0xFFFF0000u) | pair);
}
#endif

__global__ void __launch_bounds__(64) k_detect(const int* __restrict__ ei, int* __restrict__ flag) {
  int t = threadIdx.x;
  int v = ei[2 * t + 1];
  unsigned long long m = __ballot(v != 0);
  if (t == 0) *flag = (m == 0ull) ? 1 : 0;
}

// x fp32 -> fp8 e4m3 (thread: 8 values, 32B in -> 8B out)
__global__ void __launch_bounds__(256) k_prep_x(const float4* __restrict__ x4, uint2* __restrict__ xq8, int total8) {
  int i = blockIdx.x * 256 + threadIdx.x;
  if (i >= total8) return;
  float4 v0 = x4[2 * i], v1 = x4[2 * i + 1];
  unsigned w0 = fp8pack2<false>(0u, v0.x, v0.y);
  w0 = fp8pack2<true>(w0, v0.z, v0.w);
  unsigned w1 = fp8pack2<false>(0u, v1.x, v1.y);
  w1 = fp8pack2<true>(w1, v1.z, v1.w);
  xq8[i] = make_uint2(w0, w1);
}

// W1[256][128], W2[64][256] -> bf16 MFMA B-fragment order.
__global__ void __launch_bounds__(256) k_prep_w(const float* __restrict__ W1, const float* __restrict__ W2,
                                                ushort* __restrict__ W1f, ushort* __restrict__ W2f) {
  int idx = blockIdx.x * 256 + threadIdx.x;
  if (idx < 32768) {
    int jt = idx >> 11, rem = idx & 2047;
    int kt = rem >> 9, rem2 = rem & 511;
    int l = rem2 >> 3, e = rem2 & 7;
    int k = kt * 32 + (l >> 4) * 8 + e;
    int j = jt * 16 + (l & 15);
    W1f[idx] = f2bf(W1[j * 128 + k]);
  } else {
    int i2 = idx - 32768;
    if (i2 < 16384) {
      int ot = i2 >> 12, rem = i2 & 4095;
      int kt = rem >> 9;
      int l = (rem >> 3) & 63, e = rem & 7;
      int k = kt * 32 + (l >> 4) * 8 + e;
      int o = ot * 16 + (l & 15);
      W2f[i2] = f2bf(W2[o * 256 + k]);
    }
  }
}

__global__ void __launch_bounds__(256) k_bhist(const int* __restrict__ ei, const int* __restrict__ flag,
                                               int* __restrict__ bcnt, int E, int NB) {
  __shared__ int h[128];
  int t = threadIdx.x;
  if (t < 128) h[t] = 0;
  __syncthreads();
  bool f64 = (*flag != 0);
  int stride = gridDim.x * 256;
  for (int e = blockIdx.x * 256 + t; e < E; e += stride) {
    int d;
    if (f64) d = (int)((const long long*)ei)[(size_t)E + e];
    else     d = ei[(size_t)E + e];
    atomicAdd(&h[d >> BSHIFT], 1);
  }
  __syncthreads();
  if (t < NB && h[t]) atomicAdd(&bcnt[t], h[t]);
}

__global__ void __launch_bounds__(128) k_bscan(const int* __restrict__ bcnt, int* __restrict__ bbase,
                                               int* __restrict__ bcur, int* __restrict__ row_ptr,
                                               int NB, int N, int E) {
  __shared__ int s[128];
  int t = threadIdx.x;
  int v = (t < NB) ? bcnt[t] : 0;
  s[t] = v;
  __syncthreads();
  for (int o = 1; o < 128; o <<= 1) {
    int u = (t >= o) ? s[t - o] : 0;
    __syncthreads();
    s[t] += u;
    __syncthreads();
  }
  if (t < NB) {
    int base = s[t] - v;
    bbase[t] = base;
    bcur[t] = base;
  }
  if (t == 0) {
    bbase[NB] = E;
    row_ptr[N] = E;
  }
}

__global__ void __launch_bounds__(256) k_bin(const int* __restrict__ ei, const int* __restrict__ flag,
                                             int* __restrict__ bcur, int* __restrict__ gpair, int E, int NB) {
  __shared__ int hist[128], base[128], segb[128], cur[128], scanb[128];
  __shared__ int ent[TBIN];
  __shared__ int gdx[TBIN];
  int t = threadIdx.x;
  int e0 = blockIdx.x * TBIN;
  int cnt = E - e0; if (cnt > TBIN) cnt = TBIN;
  if (t < 128) hist[t] = 0;
  __syncthreads();
  bool f64 = (*flag != 0);
  int ment[16], mbk[16];
#pragma unroll
  for (int i = 0; i < 16; ++i) {
    int idx = t + i * 256;
    mbk[i] = -1;
    if (idx < cnt) {
      int e = e0 + idx;
      int s, d;
      if (f64) {
        const long long* p = (const long long*)ei;
        s = (int)p[e];
        d = (int)p[(size_t)E + e];
      } else {
        s = ei[e];
        d = ei[(size_t)E + e];
      }
      int b = d >> BSHIFT;
      mbk[i] = b;
      ment[i] = ((d & BMASK) << 17) | s;
      atomicAdd(&hist[b], 1);
    }
  }
  __syncthreads();
  if (t < 128) scanb[t] = hist[t];
  __syncthreads();
  for (int o = 1; o < 128; o <<= 1) {
    int u = 0;
    if (t < 128 && t >= o) u = scanb[t - o];
    __syncthreads();
    if (t < 128) scanb[t] += u;
    __syncthreads();
  }
  if (t < 128) {
    int b0 = scanb[t] - hist[t];
    base[t] = b0;
    cur[t] = b0;
    segb[t] = (t < NB && hist[t] > 0) ? atomicAdd(&bcur[t], hist[t]) : 0;
  }
  __syncthreads();
#pragma unroll
  for (int i = 0; i < 16; ++i) {
    int b = mbk[i];
    if (b >= 0) {
      int pos = atomicAdd(&cur[b], 1);
      ent[pos] = ment[i];
      gdx[pos] = segb[b] + (pos - base[b]);
    }
  }
  __syncthreads();
  for (int i = t; i < cnt; i += 256) gpair[gdx[i]] = ent[i];
}

__global__ void __launch_bounds__(1024) k_bcsr(const int* __restrict__ gpair, const int* __restrict__ bbase,
                                               int* __restrict__ row_ptr, float* __restrict__ inv_deg,
                                               int* __restrict__ csr, int N) {
  __shared__ int hist[1024], pre[1024], cur[1024];
  int b = blockIdx.x, t = threadIdx.x;
  int start = bbase[b], end = bbase[b + 1];
  hist[t] = 0;
  __syncthreads();
  for (int i = start + t; i < end; i += 1024) {
    int e = gpair[i];
    atomicAdd(&hist[e >> 17], 1);
  }
  __syncthreads();
  pre[t] = hist[t];
  __syncthreads();
  for (int o = 1; o < 1024; o <<= 1) {
    int u = (t >= o) ? pre[t - o] : 0;
    __syncthreads();
    pre[t] += u;
    __syncthreads();
  }
  int gbase = start + pre[t] - hist[t];
  int n = (b << BSHIFT) + t;
  if (n < N) {
    row_ptr[n] = gbase;
    inv_deg[n] = 1.0f / (float)(hist[t] > 0 ? hist[t] : 1);
  }
  cur[t] = gbase;
  __syncthreads();
  for (int i = start + t; i < end; i += 1024) {
    int e = gpair[i];
    int pos = atomicAdd(&cur[e >> 17], 1);
    csr[pos] = e & SRCMASK;
  }
}

// agg1: wave per node. 8 groups x 8 lanes; lane covers features [p*16, p*16+16) (16B fp8).
// csr idx loaded once per 64-edge chunk, shfl-distributed. 4 edges unrolled -> 4x16B in flight/lane.
__global__ void __launch_bounds__(256) k_agg1(const unsigned char* __restrict__ xq, const int* __restrict__ csr,
                                              const int* __restrict__ row_ptr, const float* __restrict__ inv_deg,
                                              ushort* __restrict__ agg1b, int N) {
  int n = blockIdx.x * 4 + (threadIdx.x >> 6);
  if (n >= N) return;
  int lane = threadIdx.x & 63;
  int g = lane >> 3, p = lane & 7;
  int s = row_ptr[n], e = row_ptr[n + 1];
  f32x2 acc[8];
#pragma unroll
  for (int k = 0; k < 8; ++k) acc[k] = (f32x2)(0.f);

#define ACC_ROW(vv)                                                        \
  do {                                                                     \
    acc[0] += fp8x2f<false>((vv).x); acc[1] += fp8x2f<true>((vv).x);       \
    acc[2] += fp8x2f<false>((vv).y); acc[3] += fp8x2f<true>((vv).y);       \
    acc[4] += fp8x2f<false>((vv).z); acc[5] += fp8x2f<true>((vv).z);       \
    acc[6] += fp8x2f<false>((vv).w); acc[7] += fp8x2f<true>((vv).w);       \
  } while (0)

  for (int base = s; base < e; base += 64) {
    int cnt = e - base; if (cnt > 64) cnt = 64;
    int ci = csr[base + (lane < cnt ? lane : cnt - 1)];
    int j = 0;
    for (; j + 31 < cnt; j += 32) {
      int i0 = __shfl(ci, j + g);
      int i1 = __shfl(ci, j + 8 + g);
      int i2 = __shfl(ci, j + 16 + g);
      int i3 = __shfl(ci, j + 24 + g);
      uint4 v0 = *(const uint4*)(xq + (size_t)i0 * 128 + p * 16);
      uint4 v1 = *(const uint4*)(xq + (size_t)i1 * 128 + p * 16);
      uint4 v2 = *(const uint4*)(xq + (size_t)i2 * 128 + p * 16);
      uint4 v3 = *(const uint4*)(xq + (size_t)i3 * 128 + p * 16);
      ACC_ROW(v0); ACC_ROW(v1); ACC_ROW(v2); ACC_ROW(v3);
    }
    for (; j + 7 < cnt; j += 8) {
      int i0 = __shfl(ci, j + g);
      uint4 v0 = *(const uint4*)(xq + (size_t)i0 * 128 + p * 16);
      ACC_ROW(v0);
    }
    if (j < cnt) {
      int sel = j + g;
      int i0 = __shfl(ci, sel < cnt ? sel : j);
      uint4 v0 = *(const uint4*)(xq + (size_t)i0 * 128 + p * 16);
      if (sel < cnt) ACC_ROW(v0);
    }
  }
#undef ACC_ROW
  // reduce across the 8 groups (lane bits 3..5)
#pragma unroll
  for (int k = 0; k < 8; ++k) {
    acc[k].x += __shfl_xor(acc[k].x, 8);  acc[k].y += __shfl_xor(acc[k].y, 8);
    acc[k].x += __shfl_xor(acc[k].x, 16); acc[k].y += __shfl_xor(acc[k].y, 16);
    acc[k].x += __shfl_xor(acc[k].x, 32); acc[k].y += __shfl_xor(acc[k].y, 32);
  }
  if (g == 0) {
    float inv = inv_deg[n];
    bf16x8 o0, o1;
#pragma unroll
    for (int k = 0; k < 4; ++k) {
      o0[2 * k]     = (short)f2bf(acc[k].x * inv);
      o0[2 * k + 1] = (short)f2bf(acc[k].y * inv);
      o1[2 * k]     = (short)f2bf(acc[4 + k].x * inv);
      o1[2 * k + 1] = (short)f2bf(acc[4 + k].y * inv);
    }
    *(bf16x8*)(agg1b + (size_t)n * 128 + p * 16) = o0;
    *(bf16x8*)(agg1b + (size_t)n * 128 + p * 16 + 8) = o1;
  }
}

// Fused MFMA MLP: g = relu(agg1 @ W1T + b1) @ W2T, bf16 in, fp8 out, fp32 accum.
__global__ void __launch_bounds__(256) k_mlp(const ushort* __restrict__ agg1b, const bf16x8* __restrict__ w1f,
                                             const float* __restrict__ b1, const bf16x8* __restrict__ w2f,
                                             unsigned char* __restrict__ gq, int N) {
  __shared__ __align__(16) ushort sm[16896];
  ushort* aT = sm;   // phase1: [64][136]
  ushort* hT = sm;   // phase2: [64][264]
  const int t = threadIdx.x;
  const int n0 = blockIdx.x * 64;

#pragma unroll
  for (int i = 0; i < 4; ++i) {
    int idx = i * 256 + t;
    int row = idx >> 4, c8 = idx & 15;
    int rr = n0 + row; if (rr >= N) rr = N - 1;
    bf16x8 v = *(const bf16x8*)(agg1b + (size_t)rr * 128 + c8 * 8);
    *(bf16x8*)(aT + row * 136 + c8 * 8) = v;
  }
  __syncthreads();

  const int w = t >> 6, l = t & 63;
  const int lm = l & 15, lq = l >> 4;

  f32x4 acc[4][4];
#pragma unroll
  for (int mt = 0; mt < 4; ++mt)
#pragma unroll
    for (int nt = 0; nt < 4; ++nt) acc[mt][nt] = (f32x4)(0.f);

#pragma unroll
  for (int kt = 0; kt < 4; ++kt) {
    bf16x8 b[4], a[4];
#pragma unroll
    for (int nt = 0; nt < 4; ++nt)
      b[nt] = w1f[((w * 4 + nt) * 4 + kt) * 64 + l];
#pragma unroll
    for (int mt = 0; mt < 4; ++mt)
      a[mt] = *(const bf16x8*)(aT + (mt * 16 + lm) * 136 + kt * 32 + lq * 8);
#pragma unroll
    for (int mt = 0; mt < 4; ++mt)
#pragma unroll
      for (int nt = 0; nt < 4; ++nt)
        acc[mt][nt] = __builtin_amdgcn_mfma_f32_16x16x32_bf16(a[mt], b[nt], acc[mt][nt], 0, 0, 0);
  }
  __syncthreads();

#pragma unroll
  for (int nt = 0; nt < 4; ++nt) {
    int col = w * 64 + nt * 16 + lm;
    float bb = b1[col];
#pragma unroll
    for (int mt = 0; mt < 4; ++mt)
#pragma unroll
      for (int r = 0; r < 4; ++r) {
        int row = mt * 16 + lq * 4 + r;
        float hv = acc[mt][nt][r] + bb;
        hT[row * 264 + col] = f2bf(fmaxf(hv, 0.f));
      }
  }
  __syncthreads();

  f32x4 acc2[4];
#pragma unroll
  for (int ot = 0; ot < 4; ++ot) acc2[ot] = (f32x4)(0.f);
#pragma unroll
  for (int kt = 0; kt < 8; ++kt) {
    bf16x8 a2 = *(const bf16x8*)(hT + (w * 16 + lm) * 264 + kt * 32 + lq * 8);
#pragma unroll
    for (int ot = 0; ot < 4; ++ot) {
      bf16x8 bf = w2f[(ot * 8 + kt) * 64 + l];
      acc2[ot] = __builtin_amdgcn_mfma_f32_16x16x32_bf16(a2, bf, acc2[ot], 0, 0, 0);
    }
  }
  // write g in fp8 e4m3
#pragma unroll
  for (int ot = 0; ot < 4; ++ot)
#pragma unroll
    for (int r = 0; r < 4; ++r) {
      int row = n0 + w * 16 + lq * 4 + r;
      if (row < N) {
        unsigned pw = fp8pack2<false>(0u, acc2[ot][r], acc2[ot][r]);
        gq[(size_t)row * 64 + ot * 16 + lm] = (unsigned char)(pw & 0xFFu);
      }
    }
}

// agg2 + b2 + log_softmax. Wave per node; 16 groups x 4 lanes; 16B fp8 per lane = 64B/edge = 1 line.
__global__ void __launch_bounds__(256) k_agg2(const unsigned char* __restrict__ gq, const int* __restrict__ csr,
                                              const int* __restrict__ row_ptr, const float* __restrict__ inv_deg,
                                              const float* __restrict__ b2, float* __restrict__ out, int N) {
  int n = blockIdx.x * 4 + (threadIdx.x >> 6);
  if (n >= N) return;
  int lane = threadIdx.x & 63;
  int g = lane >> 2, p = lane & 3;   // 16 groups x 4 lanes; lane covers features [p*16, p*16+16)
  int s = row_ptr[n], e = row_ptr[n + 1];
  f32x2 acc[8];
#pragma unroll
  for (int k = 0; k < 8; ++k) acc[k] = (f32x2)(0.f);

#define ACC_ROW(vv)                                                        \
  do {                                                                     \
    acc[0] += fp8x2f<false>((vv).x); acc[1] += fp8x2f<true>((vv).x);       \
    acc[2] += fp8x2f<false>((vv).y); acc[3] += fp8x2f<true>((vv).y);       \
    acc[4] += fp8x2f<false>((vv).z); acc[5] += fp8x2f<true>((vv).z);       \
    acc[6] += fp8x2f<false>((vv).w); acc[7] += fp8x2f<true>((vv).w);       \
  } while (0)

  for (int base = s; base < e; base += 64) {
    int cnt = e - base; if (cnt > 64) cnt = 64;
    int ci = csr[base + (lane < cnt ? lane : cnt - 1)];
    int j = 0;
    for (; j + 63 < cnt; j += 64) {
      int i0 = __shfl(ci, j + g);
      int i1 = __shfl(ci, j + 16 + g);
      int i2 = __shfl(ci, j + 32 + g);
      int i3 = __shfl(ci, j + 48 + g);
      uint4 v0 = *(const uint4*)(gq + (size_t)i0 * 64 + p * 16);
      uint4 v1 = *(const uint4*)(gq + (size_t)i1 * 64 + p * 16);
      uint4 v2 = *(const uint4*)(gq + (size_t)i2 * 64 + p * 16);
      uint4 v3 = *(const uint4*)(gq + (size_t)i3 * 64 + p * 16);
      ACC_ROW(v0); ACC_ROW(v1); ACC_ROW(v2); ACC_ROW(v3);
    }
    for (; j + 15 < cnt; j += 16) {
      int i0 = __shfl(ci, j + g);
      uint4 v0 = *(const uint4*)(gq + (size_t)i0 * 64 + p * 16);
      ACC_ROW(v0);
    }
    if (j < cnt) {
      int sel = j + g;
      int i0 = __shfl(ci, sel < cnt ? sel : j);
      uint4 v0 = *(const uint4*)(gq + (size_t)i0 * 64 + p * 16);
      if (sel < cnt) ACC_ROW(v0);
    }
  }
#undef ACC_ROW
  // reduce across the 16 groups (lane bits 2..5)
#pragma unroll
  for (int k = 0; k < 8; ++k) {
    acc[k].x += __shfl_xor(acc[k].x, 4);  acc[k].y += __shfl_xor(acc[k].y, 4);
    acc[k].x += __shfl_xor(acc[k].x, 8);  acc[k].y += __shfl_xor(acc[k].y, 8);
    acc[k].x += __shfl_xor(acc[k].x, 16); acc[k].y += __shfl_xor(acc[k].y, 16);
    acc[k].x += __shfl_xor(acc[k].x, 32); acc[k].y += __shfl_xor(acc[k].y, 32);
  }
  float inv = inv_deg[n];
  float v[16];
#pragma unroll
  for (int k = 0; k < 8; ++k) {
    v[2 * k]     = acc[k].x * inv;
    v[2 * k + 1] = acc[k].y * inv;
  }
#pragma unroll
  for (int k4 = 0; k4 < 4; ++k4) {
    float4 b = *(const float4*)(b2 + p * 16 + k4 * 4);
    v[4 * k4 + 0] += b.x; v[4 * k4 + 1] += b.y; v[4 * k4 + 2] += b.z; v[4 * k4 + 3] += b.w;
  }
  float mx = v[0];
#pragma unroll
  for (int k = 1; k < 16; ++k) mx = fmaxf(mx, v[k]);
  mx = fmaxf(mx, __shfl_xor(mx, 1));
  mx = fmaxf(mx, __shfl_xor(mx, 2));
  float se = 0.f;
#pragma unroll
  for (int k = 0; k < 16; ++k) se += expf(v[k] - mx);
  se += __shfl_xor(se, 1);
  se += __shfl_xor(se, 2);
  float lse = mx + logf(se);
  if (lane < 4) {
#pragma unroll
    for (int k4 = 0; k4 < 4; ++k4) {
      float4 o;
      o.x = v[4 * k4 + 0] - lse; o.y = v[4 * k4 + 1] - lse;
      o.z = v[4 * k4 + 2] - lse; o.w = v[4 * k4 + 3] - lse;
      *(float4*)(out + (size_t)n * 64 + p * 16 + k4 * 4) = o;
    }
  }
}

extern "C" void kernel_launch(void* const* d_in, const int* in_sizes, int n_in,
                              void* d_out, int out_size, void* d_ws, size_t ws_size,
                              hipStream_t stream) {
  const float* x  = (const float*)d_in[0];
  const int*   ei = (const int*)d_in[1];
  const float* W1 = (const float*)d_in[2];
  const float* b1 = (const float*)d_in[3];
  const float* W2 = (const float*)d_in[4];
  const float* b2 = (const float*)d_in[5];
  float* out = (float*)d_out;
  const int N = in_sizes[0] / 128;  // 100000
  const int E = in_sizes[1] / 2;    // 1600000
  const int NB = (N + BMASK) >> BSHIFT;  // 98

  char* base = (char*)d_ws;
  size_t off = 0;
  auto alloc = [&](size_t bytes) -> char* {
    char* p = base + off;
    off += (bytes + 255) & ~(size_t)255;
    return p;
  };
  int*    flag    = (int*)alloc(4);
  int*    bcnt    = (int*)alloc((size_t)NB * 4);
  int*    bbase   = (int*)alloc((size_t)(NB + 1) * 4);
  int*    bcur    = (int*)alloc((size_t)NB * 4);
  int*    gpair   = (int*)alloc((size_t)E * 4);
  int*    row_ptr = (int*)alloc((size_t)(N + 1) * 4);
  float*  inv_deg = (float*)alloc((size_t)N * 4);
  int*    csr     = (int*)alloc((size_t)E * 4);
  unsigned char* xq = (unsigned char*)alloc((size_t)N * 128);
  ushort* W1f     = (ushort*)alloc((size_t)32768 * 2);
  ushort* W2f     = (ushort*)alloc((size_t)16384 * 2);
  ushort* agg1b   = (ushort*)alloc((size_t)N * 128 * 2);
  unsigned char* gq = (unsigned char*)alloc((size_t)N * 64);
  (void)ws_size; (void)n_in; (void)out_size;

  hipMemsetAsync(bcnt, 0, (size_t)NB * 4, stream);
  k_detect<<<1, 64, 0, stream>>>(ei, flag);
  k_prep_x<<<(N * 16 + 255) / 256, 256, 0, stream>>>((const float4*)x, (uint2*)xq, N * 16);
  k_prep_w<<<192, 256, 0, stream>>>(W1, W2, W1f, W2f);
  k_bhist<<<512, 256, 0, stream>>>(ei, flag, bcnt, E, NB);
  k_bscan<<<1, 128, 0, stream>>>(bcnt, bbase, bcur, row_ptr, NB, N, E);
  k_bin<<<(E + TBIN - 1) / TBIN, 256, 0, stream>>>(ei, flag, bcur, gpair, E, NB);
  k_bcsr<<<NB, 1024, 0, stream>>>(gpair, bbase, row_ptr, inv_deg, csr, N);
  k_agg1<<<(N + 3) / 4, 256, 0, stream>>>(xq, csr, row_ptr, inv_deg, agg1b, N);
  k_mlp<<<(N + 63) / 64, 256, 0, stream>>>(agg1b, (const bf16x8*)W1f, b1, (const bf16x8*)W2f, gq, N);
  k_agg2<<<(N + 3) / 4, 256, 0, stream>>>(gq, csr, row_ptr, inv_deg, b2, out, N);
}

// Round 10
// 283.030 us; speedup vs baseline: 1.1523x; 1.1523x over previous
//
#include <hip/hip_runtime.h>

// GraphSAGE 2-layer inference.
// detect -> prep (x->fp8, W1/W2 -> MFMA-frag bf16) -> bucketed CSR build
//  -> agg1 = A_mean * x_fp8  (32 lanes/edge x 4B, shfl-distributed csr idx, fp32 acc, bf16 out)
//  -> fused MLP (bf16 MFMA): g = relu(agg1 @ W1T + b1) @ W2T -> fp8 (64B rows = 1 line/edge)
//  -> agg2 = A_mean * g_fp8 + b2 -> log_softmax (16 lanes/edge x 4B, fp32 out)
// Mean degree = 16 -> per-node epilogue matters: lane holds only 4 features so the
// cross-group shfl reduction is 4 (agg1) / 8 (agg2) ops instead of 48/64 (round-8 lesson).

typedef __attribute__((ext_vector_type(8))) short bf16x8;
typedef __attribute__((ext_vector_type(4))) float f32x4;
typedef __attribute__((ext_vector_type(2))) float f32x2;

#define BSHIFT 10
#define BMASK  1023
#define SRCMASK 0x1FFFF
#define TBIN   4096

#if __has_builtin(__builtin_amdgcn_cvt_pk_f32_fp8) && __has_builtin(__builtin_amdgcn_cvt_pk_fp8_f32)
#define HAVE_FP8_CVT 1
#else
#define HAVE_FP8_CVT 0
#endif

__device__ inline ushort f2bf(float f) {
  union { float f; unsigned u; } c; c.f = f;
  unsigned r = (c.u + 0x7fffu + ((c.u >> 16) & 1u)) >> 16;
  return (ushort)r;
}
__device__ inline float bf2f(ushort u) {
  union { unsigned u; float f; } c; c.u = ((unsigned)u) << 16;
  return c.f;
}

#if HAVE_FP8_CVT
template <bool HI>
__device__ inline f32x2 fp8x2f(unsigned w) {
  return __builtin_amdgcn_cvt_pk_f32_fp8((int)w, HI);
}
template <bool HI>
__device__ inline unsigned fp8pack2(unsigned old, float a, float b) {
  return (unsigned)__builtin_amdgcn_cvt_pk_fp8_f32(a, b, (int)old, HI);
}
#else
__device__ inline float fp8tof_1(unsigned b) {
  unsigned e = (b >> 3) & 15u, m = b & 7u;
  float v;
  if (e == 0) v = (float)m * 0x1p-9f;
  else { union { unsigned u; float f; } c; c.u = ((e + 120u) << 23) | (m << 20); v = c.f; }
  return (b & 0x80u) ? -v : v;
}
template <bool HI>
__device__ inline f32x2 fp8x2f(unsigned w) {
  unsigned sh = HI ? 16 : 0;
  f32x2 r;
  r.x = fp8tof_1((w >> sh) & 0xFFu);
  r.y = fp8tof_1((w >> (sh + 8)) & 0xFFu);
  return r;
}
__device__ inline unsigned f2fp8_1(float f) {
  float af = fabsf(f);
  unsigned s = (f < 0.f) ? 0x80u : 0u;
  if (!(af < 448.f)) return s | 0x7Eu;
  if (af < 0x1p-6f) {
    int m = (int)rintf(af * 512.0f);
    if (m >= 8) return s | 0x08u;
    return s | (unsigned)m;
  }
  int e;
  frexpf(af, &e);
  int E = e - 1;
  int q = (int)rintf(ldexpf(af, 3 - E));
  if (q >= 16) { q = 8; E += 1; if (E > 8) return s | 0x7Eu; }
  return s | ((unsigned)(E + 7) << 3) | ((unsigned)q & 7u);
}
template <bool HI>
__device__ inline unsigned fp8pack2(unsigned old, float a, float b) {
  unsigned pair = f2fp8_1(a) | (f2fp8_1(b) << 8);
  return HI ? ((old & 0x0000FFFFu) | (pair << 16)) : ((old & 0xFFFF0000u) | pair);
}
#endif

__global__ void __launch_bounds__(64) k_detect(const int* __restrict__ ei, int* __restrict__ flag) {
  int t = threadIdx.x;
  int v = ei[2 * t + 1];
  unsigned long long m = __ballot(v != 0);
  if (t == 0) *flag = (m == 0ull) ? 1 : 0;
}

// x fp32 -> fp8 e4m3 (thread: 8 values, 32B in -> 8B out)
__global__ void __launch_bounds__(256) k_prep_x(const float4* __restrict__ x4, uint2* __restrict__ xq8, int total8) {
  int i = blockIdx.x * 256 + threadIdx.x;
  if (i >= total8) return;
  float4 v0 = x4[2 * i], v1 = x4[2 * i + 1];
  unsigned w0 = fp8pack2<false>(0u, v0.x, v0.y);
  w0 = fp8pack2<true>(w0, v0.z, v0.w);
  unsigned w1 = fp8pack2<false>(0u, v1.x, v1.y);
  w1 = fp8pack2<true>(w1, v1.z, v1.w);
  xq8[i] = make_uint2(w0, w1);
}

// W1[256][128], W2[64][256] -> bf16 MFMA B-fragment order.
__global__ void __launch_bounds__(256) k_prep_w(const float* __restrict__ W1, const float* __restrict__ W2,
                                                ushort* __restrict__ W1f, ushort* __restrict__ W2f) {
  int idx = blockIdx.x * 256 + threadIdx.x;
  if (idx < 32768) {
    int jt = idx >> 11, rem = idx & 2047;
    int kt = rem >> 9, rem2 = rem & 511;
    int l = rem2 >> 3, e = rem2 & 7;
    int k = kt * 32 + (l >> 4) * 8 + e;
    int j = jt * 16 + (l & 15);
    W1f[idx] = f2bf(W1[j * 128 + k]);
  } else {
    int i2 = idx - 32768;
    if (i2 < 16384) {
      int ot = i2 >> 12, rem = i2 & 4095;
      int kt = rem >> 9;
      int l = (rem >> 3) & 63, e = rem & 7;
      int k = kt * 32 + (l >> 4) * 8 + e;
      int o = ot * 16 + (l & 15);
      W2f[i2] = f2bf(W2[o * 256 + k]);
    }
  }
}

__global__ void __launch_bounds__(256) k_bhist(const int* __restrict__ ei, const int* __restrict__ flag,
                                               int* __restrict__ bcnt, int E, int NB) {
  __shared__ int h[128];
  int t = threadIdx.x;
  if (t < 128) h[t] = 0;
  __syncthreads();
  bool f64 = (*flag != 0);
  int stride = gridDim.x * 256;
  for (int e = blockIdx.x * 256 + t; e < E; e += stride) {
    int d;
    if (f64) d = (int)((const long long*)ei)[(size_t)E + e];
    else     d = ei[(size_t)E + e];
    atomicAdd(&h[d >> BSHIFT], 1);
  }
  __syncthreads();
  if (t < NB && h[t]) atomicAdd(&bcnt[t], h[t]);
}

__global__ void __launch_bounds__(128) k_bscan(const int* __restrict__ bcnt, int* __restrict__ bbase,
                                               int* __restrict__ bcur, int* __restrict__ row_ptr,
                                               int NB, int N, int E) {
  __shared__ int s[128];
  int t = threadIdx.x;
  int v = (t < NB) ? bcnt[t] : 0;
  s[t] = v;
  __syncthreads();
  for (int o = 1; o < 128; o <<= 1) {
    int u = (t >= o) ? s[t - o] : 0;
    __syncthreads();
    s[t] += u;
    __syncthreads();
  }
  if (t < NB) {
    int base = s[t] - v;
    bbase[t] = base;
    bcur[t] = base;
  }
  if (t == 0) {
    bbase[NB] = E;
    row_ptr[N] = E;
  }
}

__global__ void __launch_bounds__(256) k_bin(const int* __restrict__ ei, const int* __restrict__ flag,
                                             int* __restrict__ bcur, int* __restrict__ gpair, int E, int NB) {
  __shared__ int hist[128], base[128], segb[128], cur[128], scanb[128];
  __shared__ int ent[TBIN];
  __shared__ int gdx[TBIN];
  int t = threadIdx.x;
  int e0 = blockIdx.x * TBIN;
  int cnt = E - e0; if (cnt > TBIN) cnt = TBIN;
  if (t < 128) hist[t] = 0;
  __syncthreads();
  bool f64 = (*flag != 0);
  int ment[16], mbk[16];
#pragma unroll
  for (int i = 0; i < 16; ++i) {
    int idx = t + i * 256;
    mbk[i] = -1;
    if (idx < cnt) {
      int e = e0 + idx;
      int s, d;
      if (f64) {
        const long long* p = (const long long*)ei;
        s = (int)p[e];
        d = (int)p[(size_t)E + e];
      } else {
        s = ei[e];
        d = ei[(size_t)E + e];
      }
      int b = d >> BSHIFT;
      mbk[i] = b;
      ment[i] = ((d & BMASK) << 17) | s;
      atomicAdd(&hist[b], 1);
    }
  }
  __syncthreads();
  if (t < 128) scanb[t] = hist[t];
  __syncthreads();
  for (int o = 1; o < 128; o <<= 1) {
    int u = 0;
    if (t < 128 && t >= o) u = scanb[t - o];
    __syncthreads();
    if (t < 128) scanb[t] += u;
    __syncthreads();
  }
  if (t < 128) {
    int b0 = scanb[t] - hist[t];
    base[t] = b0;
    cur[t] = b0;
    segb[t] = (t < NB && hist[t] > 0) ? atomicAdd(&bcur[t], hist[t]) : 0;
  }
  __syncthreads();
#pragma unroll
  for (int i = 0; i < 16; ++i) {
    int b = mbk[i];
    if (b >= 0) {
      int pos = atomicAdd(&cur[b], 1);
      ent[pos] = ment[i];
      gdx[pos] = segb[b] + (pos - base[b]);
    }
  }
  __syncthreads();
  for (int i = t; i < cnt; i += 256) gpair[gdx[i]] = ent[i];
}

__global__ void __launch_bounds__(1024) k_bcsr(const int* __restrict__ gpair, const int* __restrict__ bbase,
                                               int* __restrict__ row_ptr, float* __restrict__ inv_deg,
                                               int* __restrict__ csr, int N) {
  __shared__ int hist[1024], pre[1024], cur[1024];
  int b = blockIdx.x, t = threadIdx.x;
  int start = bbase[b], end = bbase[b + 1];
  hist[t] = 0;
  __syncthreads();
  for (int i = start + t; i < end; i += 1024) {
    int e = gpair[i];
    atomicAdd(&hist[e >> 17], 1);
  }
  __syncthreads();
  pre[t] = hist[t];
  __syncthreads();
  for (int o = 1; o < 1024; o <<= 1) {
    int u = (t >= o) ? pre[t - o] : 0;
    __syncthreads();
    pre[t] += u;
    __syncthreads();
  }
  int gbase = start + pre[t] - hist[t];
  int n = (b << BSHIFT) + t;
  if (n < N) {
    row_ptr[n] = gbase;
    inv_deg[n] = 1.0f / (float)(hist[t] > 0 ? hist[t] : 1);
  }
  cur[t] = gbase;
  __syncthreads();
  for (int i = start + t; i < end; i += 1024) {
    int e = gpair[i];
    int pos = atomicAdd(&cur[e >> 17], 1);
    csr[pos] = e & SRCMASK;
  }
}

// agg1: wave per node. 32 lanes/edge, lane covers 4 features (4B fp8 dword at xq[row*128+p*4]).
// 2 edge-groups x 4-edge unroll -> 8 loads in flight. Reduction: 4 shfl (1 level).
__global__ void __launch_bounds__(256) k_agg1(const unsigned char* __restrict__ xq, const int* __restrict__ csr,
                                              const int* __restrict__ row_ptr, const float* __restrict__ inv_deg,
                                              ushort* __restrict__ agg1b, int N) {
  int n = blockIdx.x * 4 + (threadIdx.x >> 6);
  if (n >= N) return;
  int lane = threadIdx.x & 63;
  int half = lane >> 5, p = lane & 31;
  int s = row_ptr[n], e = row_ptr[n + 1];
  f32x2 a0 = (f32x2)(0.f), a1 = (f32x2)(0.f);

  for (int base = s; base < e; base += 64) {
    int cnt = e - base; if (cnt > 64) cnt = 64;
    int ci = csr[base + (lane < cnt ? lane : cnt - 1)];
    int j = 0;
    for (; j + 7 < cnt; j += 8) {
      int i0 = __shfl(ci, j + half);
      int i1 = __shfl(ci, j + 2 + half);
      int i2 = __shfl(ci, j + 4 + half);
      int i3 = __shfl(ci, j + 6 + half);
      unsigned w0 = *(const unsigned*)(xq + (size_t)i0 * 128 + p * 4);
      unsigned w1 = *(const unsigned*)(xq + (size_t)i1 * 128 + p * 4);
      unsigned w2 = *(const unsigned*)(xq + (size_t)i2 * 128 + p * 4);
      unsigned w3 = *(const unsigned*)(xq + (size_t)i3 * 128 + p * 4);
      a0 += fp8x2f<false>(w0); a1 += fp8x2f<true>(w0);
      a0 += fp8x2f<false>(w1); a1 += fp8x2f<true>(w1);
      a0 += fp8x2f<false>(w2); a1 += fp8x2f<true>(w2);
      a0 += fp8x2f<false>(w3); a1 += fp8x2f<true>(w3);
    }
    for (; j + 1 < cnt; j += 2) {
      int i0 = __shfl(ci, j + half);
      unsigned w0 = *(const unsigned*)(xq + (size_t)i0 * 128 + p * 4);
      a0 += fp8x2f<false>(w0); a1 += fp8x2f<true>(w0);
    }
    if (j < cnt) {
      int i0 = __shfl(ci, j);
      unsigned w0 = *(const unsigned*)(xq + (size_t)i0 * 128 + p * 4);
      if (half == 0) { a0 += fp8x2f<false>(w0); a1 += fp8x2f<true>(w0); }
    }
  }
  // reduce across the 2 halves (lane bit 5): 4 shfl
  a0.x += __shfl_xor(a0.x, 32); a0.y += __shfl_xor(a0.y, 32);
  a1.x += __shfl_xor(a1.x, 32); a1.y += __shfl_xor(a1.y, 32);
  if (half == 0) {
    float inv = inv_deg[n];
    ushort4 o;
    o.x = f2bf(a0.x * inv); o.y = f2bf(a0.y * inv);
    o.z = f2bf(a1.x * inv); o.w = f2bf(a1.y * inv);
    *(ushort4*)(agg1b + (size_t)n * 128 + p * 4) = o;
  }
}

// Fused MFMA MLP: g = relu(agg1 @ W1T + b1) @ W2T, bf16 in, fp8 out, fp32 accum.
__global__ void __launch_bounds__(256) k_mlp(const ushort* __restrict__ agg1b, const bf16x8* __restrict__ w1f,
                                             const float* __restrict__ b1, const bf16x8* __restrict__ w2f,
                                             unsigned char* __restrict__ gq, int N) {
  __shared__ __align__(16) ushort sm[16896];
  ushort* aT = sm;   // phase1: [64][136]
  ushort* hT = sm;   // phase2: [64][264]
  const int t = threadIdx.x;
  const int n0 = blockIdx.x * 64;

#pragma unroll
  for (int i = 0; i < 4; ++i) {
    int idx = i * 256 + t;
    int row = idx >> 4, c8 = idx & 15;
    int rr = n0 + row; if (rr >= N) rr = N - 1;
    bf16x8 v = *(const bf16x8*)(agg1b + (size_t)rr * 128 + c8 * 8);
    *(bf16x8*)(aT + row * 136 + c8 * 8) = v;
  }
  __syncthreads();

  const int w = t >> 6, l = t & 63;
  const int lm = l & 15, lq = l >> 4;

  f32x4 acc[4][4];
#pragma unroll
  for (int mt = 0; mt < 4; ++mt)
#pragma unroll
    for (int nt = 0; nt < 4; ++nt) acc[mt][nt] = (f32x4)(0.f);

#pragma unroll
  for (int kt = 0; kt < 4; ++kt) {
    bf16x8 b[4], a[4];
#pragma unroll
    for (int nt = 0; nt < 4; ++nt)
      b[nt] = w1f[((w * 4 + nt) * 4 + kt) * 64 + l];
#pragma unroll
    for (int mt = 0; mt < 4; ++mt)
      a[mt] = *(const bf16x8*)(aT + (mt * 16 + lm) * 136 + kt * 32 + lq * 8);
#pragma unroll
    for (int mt = 0; mt < 4; ++mt)
#pragma unroll
      for (int nt = 0; nt < 4; ++nt)
        acc[mt][nt] = __builtin_amdgcn_mfma_f32_16x16x32_bf16(a[mt], b[nt], acc[mt][nt], 0, 0, 0);
  }
  __syncthreads();

#pragma unroll
  for (int nt = 0; nt < 4; ++nt) {
    int col = w * 64 + nt * 16 + lm;
    float bb = b1[col];
#pragma unroll
    for (int mt = 0; mt < 4; ++mt)
#pragma unroll
      for (int r = 0; r < 4; ++r) {
        int row = mt * 16 + lq * 4 + r;
        float hv = acc[mt][nt][r] + bb;
        hT[row * 264 + col] = f2bf(fmaxf(hv, 0.f));
      }
  }
  __syncthreads();

  f32x4 acc2[4];
#pragma unroll
  for (int ot = 0; ot < 4; ++ot) acc2[ot] = (f32x4)(0.f);
#pragma unroll
  for (int kt = 0; kt < 8; ++kt) {
    bf16x8 a2 = *(const bf16x8*)(hT + (w * 16 + lm) * 264 + kt * 32 + lq * 8);
#pragma unroll
    for (int ot = 0; ot < 4; ++ot) {
      bf16x8 bf = w2f[(ot * 8 + kt) * 64 + l];
      acc2[ot] = __builtin_amdgcn_mfma_f32_16x16x32_bf16(a2, bf, acc2[ot], 0, 0, 0);
    }
  }
  // write g in fp8 e4m3
#pragma unroll
  for (int ot = 0; ot < 4; ++ot)
#pragma unroll
    for (int r = 0; r < 4; ++r) {
      int row = n0 + w * 16 + lq * 4 + r;
      if (row < N) {
        unsigned pw = fp8pack2<false>(0u, acc2[ot][r], acc2[ot][r]);
        gq[(size_t)row * 64 + ot * 16 + lm] = (unsigned char)(pw & 0xFFu);
      }
    }
}

// agg2 + b2 + log_softmax. Wave per node; 16 lanes/edge, lane covers 4 features (4B fp8).
// 4 groups x 4-edge unroll -> 16 edges/round (= mean degree in one round).
// Reduction: 8 shfl (2 levels); softmax: 4 in-lane + 4-level lane shfl.
__global__ void __launch_bounds__(256) k_agg2(const unsigned char* __restrict__ gq, const int* __restrict__ csr,
                                              const int* __restrict__ row_ptr, const float* __restrict__ inv_deg,
                                              const float* __restrict__ b2, float* __restrict__ out, int N) {
  int n = blockIdx.x * 4 + (threadIdx.x >> 6);
  if (n >= N) return;
  int lane = threadIdx.x & 63;
  int q = lane >> 4, p = lane & 15;
  int s = row_ptr[n], e = row_ptr[n + 1];
  f32x2 a0 = (f32x2)(0.f), a1 = (f32x2)(0.f);

  for (int base = s; base < e; base += 64) {
    int cnt = e - base; if (cnt > 64) cnt = 64;
    int ci = csr[base + (lane < cnt ? lane : cnt - 1)];
    int j = 0;
    for (; j + 15 < cnt; j += 16) {
      int i0 = __shfl(ci, j + q);
      int i1 = __shfl(ci, j + 4 + q);
      int i2 = __shfl(ci, j + 8 + q);
      int i3 = __shfl(ci, j + 12 + q);
      unsigned w0 = *(const unsigned*)(gq + (size_t)i0 * 64 + p * 4);
      unsigned w1 = *(const unsigned*)(gq + (size_t)i1 * 64 + p * 4);
      unsigned w2 = *(const unsigned*)(gq + (size_t)i2 * 64 + p * 4);
      unsigned w3 = *(const unsigned*)(gq + (size_t)i3 * 64 + p * 4);
      a0 += fp8x2f<false>(w0); a1 += fp8x2f<true>(w0);
      a0 += fp8x2f<false>(w1); a1 += fp8x2f<true>(w1);
      a0 += fp8x2f<false>(w2); a1 += fp8x2f<true>(w2);
      a0 += fp8x2f<false>(w3); a1 += fp8x2f<true>(w3);
    }
    for (; j + 3 < cnt; j += 4) {
      int i0 = __shfl(ci, j + q);
      unsigned w0 = *(const unsigned*)(gq + (size_t)i0 * 64 + p * 4);
      a0 += fp8x2f<false>(w0); a1 += fp8x2f<true>(w0);
    }
    if (j < cnt) {
      int sel = j + q;
      int i0 = __shfl(ci, sel < cnt ? sel : j);
      unsigned w0 = *(const unsigned*)(gq + (size_t)i0 * 64 + p * 4);
      if (sel < cnt) { a0 += fp8x2f<false>(w0); a1 += fp8x2f<true>(w0); }
    }
  }
  // reduce across 4 groups (lane bits 4,5): 8 shfl
  a0.x += __shfl_xor(a0.x, 16); a0.y += __shfl_xor(a0.y, 16);
  a1.x += __shfl_xor(a1.x, 16); a1.y += __shfl_xor(a1.y, 16);
  a0.x += __shfl_xor(a0.x, 32); a0.y += __shfl_xor(a0.y, 32);
  a1.x += __shfl_xor(a1.x, 32); a1.y += __shfl_xor(a1.y, 32);
  float inv = inv_deg[n];
  float4 b = *(const float4*)(b2 + p * 4);
  float4 v;
  v.x = a0.x * inv + b.x;
  v.y = a0.y * inv + b.y;
  v.z = a1.x * inv + b.z;
  v.w = a1.y * inv + b.w;
  float mx = fmaxf(fmaxf(v.x, v.y), fmaxf(v.z, v.w));
#pragma unroll
  for (int off = 1; off <= 8; off <<= 1) mx = fmaxf(mx, __shfl_xor(mx, off));
  float se = expf(v.x - mx) + expf(v.y - mx) + expf(v.z - mx) + expf(v.w - mx);
#pragma unroll
  for (int off = 1; off <= 8; off <<= 1) se += __shfl_xor(se, off);
  float lse = mx + logf(se);
  v.x -= lse; v.y -= lse; v.z -= lse; v.w -= lse;
  if (q == 0) *(float4*)(out + (size_t)n * 64 + p * 4) = v;
}

extern "C" void kernel_launch(void* const* d_in, const int* in_sizes, int n_in,
                              void* d_out, int out_size, void* d_ws, size_t ws_size,
                              hipStream_t stream) {
  const float* x  = (const float*)d_in[0];
  const int*   ei = (const int*)d_in[1];
  const float* W1 = (const float*)d_in[2];
  const float* b1 = (const float*)d_in[3];
  const float* W2 = (const float*)d_in[4];
  const float* b2 = (const float*)d_in[5];
  float* out = (float*)d_out;
  const int N = in_sizes[0] / 128;  // 100000
  const int E = in_sizes[1] / 2;    // 1600000
  const int NB = (N + BMASK) >> BSHIFT;  // 98

  char* base = (char*)d_ws;
  size_t off = 0;
  auto alloc = [&](size_t bytes) -> char* {
    char* p = base + off;
    off += (bytes + 255) & ~(size_t)255;
    return p;
  };
  int*    flag    = (int*)alloc(4);
  int*    bcnt    = (int*)alloc((size_t)NB * 4);
  int*    bbase   = (int*)alloc((size_t)(NB + 1) * 4);
  int*    bcur    = (int*)alloc((size_t)NB * 4);
  int*    gpair   = (int*)alloc((size_t)E * 4);
  int*    row_ptr = (int*)alloc((size_t)(N + 1) * 4);
  float*  inv_deg = (float*)alloc((size_t)N * 4);
  int*    csr     = (int*)alloc((size_t)E * 4);
  unsigned char* xq = (unsigned char*)alloc((size_t)N * 128);
  ushort* W1f     = (ushort*)alloc((size_t)32768 * 2);
  ushort* W2f     = (ushort*)alloc((size_t)16384 * 2);
  ushort* agg1b   = (ushort*)alloc((size_t)N * 128 * 2);
  unsigned char* gq = (unsigned char*)alloc((size_t)N * 64);
  (void)ws_size; (void)n_in; (void)out_size;

  hipMemsetAsync(bcnt, 0, (size_t)NB * 4, stream);
  k_detect<<<1, 64, 0, stream>>>(ei, flag);
  k_prep_x<<<(N * 16 + 255) / 256, 256, 0, stream>>>((const float4*)x, (uint2*)xq, N * 16);
  k_prep_w<<<192, 256, 0, stream>>>(W1, W2, W1f, W2f);
  k_bhist<<<512, 256, 0, stream>>>(ei, flag, bcnt, E, NB);
  k_bscan<<<1, 128, 0, stream>>>(bcnt, bbase, bcur, row_ptr, NB, N, E);
  k_bin<<<(E + TBIN - 1) / TBIN, 256, 0, stream>>>(ei, flag, bcur, gpair, E, NB);
  k_bcsr<<<NB, 1024, 0, stream>>>(gpair, bbase, row_ptr, inv_deg, csr, N);
  k_agg1<<<(N + 3) / 4, 256, 0, stream>>>(xq, csr, row_ptr, inv_deg, agg1b, N);
  k_mlp<<<(N + 63) / 64, 256, 0, stream>>>(agg1b, (const bf16x8*)W1f, b1, (const bf16x8*)W2f, gq, N);
  k_agg2<<<(N + 3) / 4, 256, 0, stream>>>(gq, csr, row_ptr, inv_deg, b2, out, N);
}